// Round 1
// baseline (3507.597 us; speedup 1.0000x reference)
//
#include <hip/hip_runtime.h>
#include <math.h>

#define DEV static __device__ __forceinline__

// ---- problem constants ----
#define B_   2
#define N_   4
#define T_   512
#define D_   1024
#define DK_  64
#define H_   8
#define E_   6
#define DV_  64
#define DKP_ 128
#define HE_  48
#define R_   16
#define DA_  103
#define CC_  512
#define DPG_ 316
#define ND_  4096
#define U_   1024      // B*T tokens

struct P {
  // inputs
  const float *stream, *freqs, *pope_delta;
  const float *W_q, *W_k, *W_v, *q_rw, *kv_rw;
  const float *lA_q, *lB_q, *lA_k, *lB_k, *lA_v, *lB_v;
  const float *a_up, *a_dn, *b_up, *b_dn;
  const float *mhc_norm, *phi_pre, *phi_post, *phi_res;
  const float *b_pre, *b_post, *b_res, *al_pre, *al_post, *al_res;
  const float *bn_w, *W_pre, *W_o, *W_pg1, *W_pg2;
  // workspace
  int *qsel, *kvsel, *qcnt, *kvcnt, *qlist, *kvlist;
  float *scale, *phiT, *mhc_logits;
  float *Hpre_q, *Hpre_kv, *Hres, *Hpost;
  float *he_kv, *he_q;
  float *WqT, *WkT, *WvT, *WoT;
  float *kv_lin, *aup, *bup, *pre_logit, *pg, *post_logit;
  float *la_k, *la_v, *la_q, *q_lin;
  float *a_buf, *b_buf, *q_buf, *k_buf, *v_buf;
  float *attn, *g, *y;
  float *out;
};

DEV float sigm(float x){ return 1.f/(1.f+expf(-x)); }
DEV float softplus_(float x){ return x>0.f ? x+log1pf(expf(-x)) : log1pf(expf(x)); }
DEV float silu_(float x){ return x*sigm(x); }

DEV float block_reduce_sum(float v, float* sm){
  __syncthreads();  // make sm reusable
  int lane = threadIdx.x & 63, w = threadIdx.x >> 6;
  for (int off=32; off; off>>=1) v += __shfl_down(v, off, 64);
  if (lane==0) sm[w] = v;
  __syncthreads();
  if (threadIdx.x == 0){
    float s = 0; int nw = blockDim.x >> 6;
    for (int i=0;i<nw;i++) s += sm[i];
    sm[0] = s;
  }
  __syncthreads();
  return sm[0];
}

// ---- generic transpose: dst[m][c][r] = src[m][r][c] ----
__global__ void k_tr(const float* src, float* dst, int R, int C){
  int m = blockIdx.x;
  int idx = blockIdx.y*256 + threadIdx.x;
  if (idx >= R*C) return;
  int r = idx / C, c = idx % C;
  dst[(size_t)m*R*C + (size_t)c*R + r] = src[(size_t)m*R*C + (size_t)r*C + c];
}

// ---- phiT[d][j] = phi_row(j)[d] * mhc_norm[k][d],  j = k*24+r ----
__global__ void k_phiT(P p){
  int j = blockIdx.x; int k = j/24, r = j%24;
  const float* src;
  if (r < 4)      src = p.phi_pre  + (size_t)(k*4+r)*ND_;
  else if (r < 8) src = p.phi_post + (size_t)(k*4+(r-4))*ND_;
  else            src = p.phi_res  + (size_t)(k*16+(r-8))*ND_;
  const float* mn = p.mhc_norm + (size_t)k*ND_;
  for (int d = threadIdx.x; d < ND_; d += 256)
    p.phiT[(size_t)d*1152 + j] = src[d]*mn[d];
}

// ---- routing: route_in = mean_n stream; argmax over E (post-clip, first-max) ----
__global__ void k_route(P p){
  int u = blockIdx.x, b = u>>9, t = u&511;
  __shared__ float ri[D_];
  __shared__ float lg[2][HE_];
  int tid = threadIdx.x;
  for (int d = tid; d < D_; d += 256){
    float s = 0;
    #pragma unroll
    for (int n = 0; n < N_; n++) s += p.stream[(((size_t)(b*N_+n)*T_)+t)*D_ + d];
    ri[d] = s * 0.25f;
  }
  __syncthreads();
  int lane = tid & 63, wv = tid >> 6;
  for (int j = wv; j < 2*HE_; j += 4){
    const float* w = (j < HE_ ? p.q_rw : p.kv_rw) + (size_t)(j % HE_)*D_;
    float acc = 0;
    for (int d = lane; d < D_; d += 64) acc += ri[d]*w[d];
    for (int off=32; off; off>>=1) acc += __shfl_down(acc, off, 64);
    if (lane==0) lg[j/HE_][j%HE_] = acc;
  }
  __syncthreads();
  if (tid < 16){
    int h = tid & 7, which = tid >> 3;
    const float* L = lg[which] + h*E_;
    float best = fminf(fmaxf(L[0],-10.f),10.f); int bi=0;
    for (int e=1;e<E_;e++){ float v=fminf(fmaxf(L[e],-10.f),10.f); if (v>best){best=v;bi=e;} }
    int g = h*E_+bi;
    if (which==0){ p.qsel[h*U_+u]=bi;  int pos=atomicAdd(&p.qcnt[g],1);  p.qlist[g*U_+pos]=u; }
    else         { p.kvsel[h*U_+u]=bi; int pos=atomicAdd(&p.kvcnt[g],1); p.kvlist[g*U_+pos]=u; }
  }
}

// ---- per-token rms scale of x (over ND) ----
__global__ void k_xscale(P p){
  int u = blockIdx.x, b = u>>9, t = u&511;
  __shared__ float sm[8];
  float ss = 0;
  for (int i = threadIdx.x; i < ND_; i += 256){
    int n = i >> 10, d = i & 1023;
    float v = p.stream[(((size_t)(b*N_+n)*T_)+t)*D_ + d];
    ss += v*v;
  }
  ss = block_reduce_sum(ss, sm);
  if (threadIdx.x==0) p.scale[u] = rsqrtf(ss/(float)ND_ + 1e-8f);
}

// ---- unified f32 tiled GEMM; MODE 0:mhc 1:kv-wide 2:q 3:pg2 4:y ----
#define BM 64
#define BN 64
#define BK 32

template<int MODE>
__global__ __launch_bounds__(256) void k_gemm(P p){
  const int n0 = blockIdx.x * BN;
  const int m0 = blockIdx.y * BM;
  const int g  = blockIdx.z;
  const int h  = g / E_;
  int K, NO, cnt;
  const int* list = nullptr;
  if (MODE==0){ K=ND_;  NO=1152; cnt=U_; }
  else if (MODE==1){ K=D_;   NO=1194; cnt=p.kvcnt[g]; list=p.kvlist + g*U_; }
  else if (MODE==2){ K=D_;   NO=80;   cnt=p.qcnt[g];  list=p.qlist  + g*U_; }
  else if (MODE==3){ K=DPG_; NO=D_;   cnt=p.kvcnt[g]; list=p.kvlist + g*U_; }
  else { K=CC_; NO=D_; cnt=U_; }
  if (m0 >= cnt) return;
  const int rows = min(BM, cnt - m0);

  __shared__ float As[BM][BK+1];
  __shared__ float Bs[BK][BN+4];
  __shared__ int toks[BM];
  int tid = threadIdx.x;
  if (tid < BM){
    if (MODE==1||MODE==2||MODE==3) toks[tid] = (tid < rows) ? list[m0+tid] : 0;
    else toks[tid] = m0 + tid;
  }
  __syncthreads();

  float acc[4][4];
  #pragma unroll
  for (int i=0;i<4;i++){
    #pragma unroll
    for(int j=0;j<4;j++) acc[i][j]=0.f;
  }
  const int tx = tid & 15, ty = tid >> 4;

  for (int k0 = 0; k0 < K; k0 += BK){
    #pragma unroll
    for (int i=0;i<8;i++){          // stage A (64x32)
      int idx = tid + 256*i;
      int r = idx >> 5, kk = idx & 31;
      int kg = k0 + kk;
      float v = 0.f;
      if (r < rows && kg < K){
        int u = toks[r];
        if (MODE==0){
          int b=u>>9, t=u&511, n=kg>>10, d=kg&1023;
          v = p.stream[(((size_t)(b*N_+n)*T_)+t)*D_ + d] * p.scale[u];
        } else if (MODE==1){
          v = p.he_kv[((size_t)(h*U_+u))*D_ + kg];
        } else if (MODE==2){
          v = p.he_q[((size_t)(h*U_+u))*D_ + kg];
        } else if (MODE==3){
          v = p.pg[((size_t)(h*U_+u))*DPG_ + kg];
        } else {
          v = p.g[(size_t)u*CC_ + kg];
        }
      }
      As[r][kk] = v;
    }
    #pragma unroll
    for (int i=0;i<8;i++){          // stage B (32x64)
      int idx = tid + 256*i;
      int kk = idx >> 6, c = idx & 63;
      int kg = k0 + kk, cg = n0 + c;
      float v = 0.f;
      if (kg < K && cg < NO){
        if (MODE==0) v = p.phiT[(size_t)kg*1152 + cg];
        else if (MODE==1){
          const float* ptr; int ld, loc;
          if (cg < 64){        ptr = p.WkT   + (size_t)h*D_*64;   ld=64;   loc=cg; }
          else if (cg < 128){  ptr = p.WvT   + (size_t)h*D_*64;   ld=64;   loc=cg-64; }
          else if (cg < 231){  ptr = p.a_up  + (size_t)g*D_*DA_;  ld=DA_;  loc=cg-128; }
          else if (cg < 334){  ptr = p.b_up  + (size_t)g*D_*DA_;  ld=DA_;  loc=cg-231; }
          else if (cg < 846){  ptr = p.W_pre + (size_t)g*D_*CC_;  ld=CC_;  loc=cg-334; }
          else if (cg < 1162){ ptr = p.W_pg1 + (size_t)g*D_*DPG_; ld=DPG_; loc=cg-846; }
          else if (cg < 1178){ ptr = p.lA_k  + (size_t)g*D_*R_;   ld=R_;   loc=cg-1162; }
          else {               ptr = p.lA_v  + (size_t)g*D_*R_;   ld=R_;   loc=cg-1178; }
          v = ptr[(size_t)kg*ld + loc];
        }
        else if (MODE==2){
          if (cg < 64) v = p.WqT[(size_t)h*D_*64 + (size_t)kg*64 + cg];
          else v = p.lA_q[(size_t)g*D_*R_ + (size_t)kg*R_ + (cg-64)];
        }
        else if (MODE==3) v = p.W_pg2[(size_t)g*DPG_*D_ + (size_t)kg*D_ + cg];
        else v = p.WoT[(size_t)kg*D_ + cg];
      }
      Bs[kk][c] = v;
    }
    __syncthreads();
    #pragma unroll
    for (int kk=0; kk<BK; kk++){
      float a[4], bv[4];
      #pragma unroll
      for (int i=0;i<4;i++) a[i] = As[ty*4+i][kk];
      #pragma unroll
      for (int j=0;j<4;j++) bv[j] = Bs[kk][tx*4+j];
      #pragma unroll
      for (int i=0;i<4;i++){
        #pragma unroll
        for (int j=0;j<4;j++) acc[i][j] += a[i]*bv[j];
      }
    }
    __syncthreads();
  }

  #pragma unroll
  for (int i=0;i<4;i++){
    int r = ty*4+i;
    if (r >= rows) continue;
    int u = toks[r];
    #pragma unroll
    for (int j=0;j<4;j++){
      int cg = n0 + tx*4+j;
      if (cg >= NO) continue;
      float v = acc[i][j];
      if (MODE==0){
        p.mhc_logits[(size_t)u*1152 + cg] = v;
      } else if (MODE==1){
        size_t base = (size_t)(h*U_+u);
        if (cg < 128)       p.kv_lin[base*128 + cg] = v;
        else if (cg < 231)  p.aup[base*DA_ + (cg-128)] = silu_(v);
        else if (cg < 334)  p.bup[base*DA_ + (cg-231)] = silu_(v);
        else if (cg < 846)  atomicAdd(&p.pre_logit[(size_t)u*CC_ + (cg-334)], v);
        else if (cg < 1162) p.pg[base*DPG_ + (cg-846)] = silu_(v);
        else if (cg < 1178) p.la_k[base*R_ + (cg-1162)] = silu_(v);
        else                p.la_v[base*R_ + (cg-1178)] = silu_(v);
      } else if (MODE==2){
        size_t base = (size_t)(h*U_+u);
        if (cg < 64) p.q_lin[base*64 + cg] = v;
        else         p.la_q[base*R_ + (cg-64)] = silu_(v);
      } else if (MODE==3){
        atomicAdd(&p.post_logit[(size_t)u*D_ + cg], v);
      } else {
        p.y[(size_t)u*D_ + cg] = v * sigm(p.post_logit[(size_t)u*D_ + cg]);
      }
    }
  }
}

// ---- selected-expert MHC gates + sinkhorn ----
__global__ void k_mhcsel(P p){
  int u = blockIdx.x;
  int tid = threadIdx.x;
  __shared__ float racc[8][16];
  __shared__ float pacc[8][4];
  if (tid < 8){
    int h = tid;
    const float* lg = p.mhc_logits + (size_t)u*1152;
    int kq = h*E_ + p.qsel[h*U_+u];
    for (int n=0;n<4;n++)
      p.Hpre_q[(size_t)(h*U_+u)*4 + n] = sigm(p.al_pre[kq]*lg[kq*24+n] + p.b_pre[kq*4+n]);
    int kk = h*E_ + p.kvsel[h*U_+u];
    for (int n=0;n<4;n++)
      p.Hpre_kv[(size_t)(h*U_+u)*4 + n] = sigm(p.al_pre[kk]*lg[kk*24+n] + p.b_pre[kk*4+n]);
    for (int n=0;n<4;n++)
      pacc[h][n] = 2.f*sigm(p.al_post[kk]*lg[kk*24+4+n] + p.b_post[kk*4+n]);
    float M[4][4];
    for (int n=0;n<4;n++)
      for (int m=0;m<4;m++)
        M[n][m] = expf(p.al_res[kk]*lg[kk*24+8+n*4+m] + p.b_res[kk*16+n*4+m]);
    for (int it=0; it<6; it++){
      for (int n=0;n<4;n++){ float s=M[n][0]+M[n][1]+M[n][2]+M[n][3]; float r=1.f/s;
        for(int m=0;m<4;m++) M[n][m]*=r; }
      for (int m=0;m<4;m++){ float s=M[0][m]+M[1][m]+M[2][m]+M[3][m]; float r=1.f/s;
        for(int n=0;n<4;n++) M[n][m]*=r; }
    }
    for (int n=0;n<4;n++) for (int m=0;m<4;m++) racc[h][n*4+m] = M[n][m];
  }
  __syncthreads();
  if (tid < 16){
    float s=0; for (int h=0;h<8;h++) s += racc[h][tid];
    p.Hres[(size_t)u*16 + tid] = s * 0.125f;
  }
  if (tid < 4){
    float s=0; for (int h=0;h<8;h++) s += pacc[h][tid];
    p.Hpost[(size_t)u*4 + tid] = s * 0.125f;
  }
}

// ---- h_e rows (selected experts only): path0=q, path1=kv ----
__global__ void k_he(P p){
  int id = blockIdx.x;
  int path = id >> 13;
  int h = (id >> 10) & 7;
  int u = id & 1023;
  int b = u>>9, t = u&511;
  int sel = path ? p.kvsel[h*U_+u] : p.qsel[h*U_+u];
  int k = h*E_ + sel;
  const float* Hp = (path ? p.Hpre_kv : p.Hpre_q) + (size_t)(h*U_+u)*4;
  float w0=Hp[0], w1=Hp[1], w2=Hp[2], w3=Hp[3];
  float v[4];
  float ss = 0;
  int tid = threadIdx.x;
  #pragma unroll
  for (int j=0;j<4;j++){
    int d = tid + j*256;
    float s0 = p.stream[(((size_t)(b*N_+0)*T_)+t)*D_ + d];
    float s1 = p.stream[(((size_t)(b*N_+1)*T_)+t)*D_ + d];
    float s2 = p.stream[(((size_t)(b*N_+2)*T_)+t)*D_ + d];
    float s3 = p.stream[(((size_t)(b*N_+3)*T_)+t)*D_ + d];
    v[j] = w0*s0 + w1*s1 + w2*s2 + w3*s3;
    ss += v[j]*v[j];
  }
  __shared__ float sm[8];
  ss = block_reduce_sum(ss, sm);
  float sc = rsqrtf(ss/(float)D_ + 1e-8f);
  float* out = (path ? p.he_kv : p.he_q) + (size_t)(h*U_+u)*D_;
  #pragma unroll
  for (int j=0;j<4;j++){
    int d = tid + j*256;
    out[d] = v[j]*sc*p.bn_w[(size_t)k*D_ + d];
  }
}

// ---- kv second stage: alpha_down/beta_down, loraB, l2n + PoPE for k, v ----
__global__ void k_stage2(P p){
  int id = blockIdx.x;
  int h = id >> 10, u = id & 1023;
  int t = u & 511;
  int k = h*E_ + p.kvsel[h*U_+u];
  size_t base = (size_t)(h*U_+u);
  __shared__ float s_au[DA_], s_bu[DA_], s_lk[R_], s_lv[R_], s_kl[64], s_vl[64];
  int tid = threadIdx.x;
  if (tid < DA_){ s_au[tid] = p.aup[base*DA_+tid]; s_bu[tid] = p.bup[base*DA_+tid]; }
  if (tid < R_){ s_lk[tid] = p.la_k[base*R_+tid]; s_lv[tid] = p.la_v[base*R_+tid]; }
  if (tid >= 64 && tid < 128){
    s_kl[tid-64] = p.kv_lin[base*128 + (tid-64)];
    s_vl[tid-64] = p.kv_lin[base*128 + 64 + (tid-64)];
  }
  __syncthreads();
  {
    float acc = 0;
    const float* W = p.a_dn + (size_t)k*DA_*DKP_;
    for (int a=0;a<DA_;a++) acc += s_au[a]*W[a*DKP_ + tid];
    p.a_buf[base*DKP_ + tid] = sigm(acc);
  }
  if (tid == 0){
    float acc = 0;
    const float* W = p.b_dn + (size_t)k*DA_;
    for (int a=0;a<DA_;a++) acc += s_bu[a]*W[a];
    p.b_buf[base] = sigm(acc);
  }
  if (tid < 64){
    int o = tid;
    float lbk=0.f, lbv=0.f;
    for (int r=0;r<R_;r++){
      lbk += s_lk[r]*p.lB_k[((size_t)k*R_+r)*DK_ + o];
      lbv += s_lv[r]*p.lB_v[((size_t)k*R_+r)*DV_ + o];
    }
    float kl = s_kl[o] + lbk;
    float ss = kl*kl;
    for (int off=1; off<64; off<<=1) ss += __shfl_xor(ss, off, 64);
    float kp = kl * rsqrtf(ss + 1e-12f);
    float mu = softplus_(kp);
    float ph = (float)t * p.freqs[o] - 6.2831855f * sigm(p.pope_delta[o]);
    p.k_buf[base*DKP_ + o]      = mu * cosf(ph);
    p.k_buf[base*DKP_ + 64 + o] = mu * sinf(ph);
    p.v_buf[base*DV_ + o] = s_vl[o] + lbv;
  }
}

// ---- q second stage ----
__global__ void k_stage2q(P p){
  int id = blockIdx.x;
  int h = id >> 10, u = id & 1023;
  int t = u & 511;
  int sel = p.qsel[h*U_+u];
  size_t base = (size_t)(h*U_+u);
  int o = threadIdx.x;
  if (sel == 0){
    p.q_buf[base*DKP_ + o] = 0.f;
    p.q_buf[base*DKP_ + 64 + o] = 0.f;
    return;
  }
  int k = h*E_ + sel;
  float lbq = 0.f;
  for (int r=0;r<R_;r++) lbq += p.la_q[base*R_+r]*p.lB_q[((size_t)k*R_+r)*DK_+o];
  float ql = p.q_lin[base*64 + o] + lbq;
  float ss = ql*ql;
  for (int off=1; off<64; off<<=1) ss += __shfl_xor(ss, off, 64);
  float qp = ql*rsqrtf(ss + 1e-12f);
  float mu = softplus_(qp);
  float ph = (float)t * p.freqs[o];
  p.q_buf[base*DKP_ + o]      = mu*cosf(ph);
  p.q_buf[base*DKP_ + 64 + o] = mu*sinf(ph);
}

// ---- KDA delta-rule scan: one block per (h,b), state in registers ----
__global__ __launch_bounds__(512) void k_scan(P p){
  int h = blockIdx.x >> 1, b = blockIdx.x & 1;
  int tid = threadIdx.x;
  int e = tid & 63, d8 = tid >> 6;
  float S[16];
  #pragma unroll
  for (int i=0;i<16;i++) S[i]=0.f;
  __shared__ float sq[128], sk[128], sa[128], sv[64];
  __shared__ float sb;
  __shared__ float part[8][64];
  __shared__ float wshr[64];
  for (int t=0;t<T_;t++){
    int u = b*T_ + t;
    size_t base = (size_t)(h*U_+u);
    if (tid < 128){ sq[tid] = p.q_buf[base*128+tid]; sk[tid] = p.k_buf[base*128+tid]; }
    else if (tid < 256){ sa[tid-128] = p.a_buf[base*128 + (tid-128)]; }
    else if (tid < 320){ sv[tid-256] = p.v_buf[base*64 + (tid-256)]; }
    else if (tid == 320){ sb = p.b_buf[base]; }
    __syncthreads();
    float pa = 0.f;
    int db = d8*16;
    #pragma unroll
    for (int i=0;i<16;i++) pa += sk[db+i]*sa[db+i]*S[i];
    part[d8][e] = pa;
    __syncthreads();
    if (tid < 64){
      float s = 0;
      #pragma unroll
      for (int j=0;j<8;j++) s += part[j][tid];
      wshr[tid] = sv[tid] - s;
    }
    __syncthreads();
    float w = wshr[e], bs = sb;
    float o = 0.f;
    #pragma unroll
    for (int i=0;i<16;i++){
      S[i] = sa[db+i]*S[i] + bs*sk[db+i]*w;
      o += sq[db+i]*S[i];
    }
    part[d8][e] = o;
    __syncthreads();
    if (tid < 64){
      float s=0;
      #pragma unroll
      for (int j=0;j<8;j++) s += part[j][tid];
      p.attn[(size_t)u*CC_ + h*64 + tid] = s;
    }
  }
}

// ---- g = attn * sigmoid(pre_logit) ----
__global__ void k_g(P p){
  int i = blockIdx.x*256 + threadIdx.x;
  if (i >= U_*CC_) return;
  p.g[i] = p.attn[i] * sigm(p.pre_logit[i]);
}

// ---- final: out[b,n,t,d] = sum_m Hres*stream + Hpost*y ----
__global__ void k_final(P p){
  int u = blockIdx.x, b=u>>9, t=u&511;
  __shared__ float hr[16], hp[4];
  if (threadIdx.x < 16) hr[threadIdx.x] = p.Hres[(size_t)u*16+threadIdx.x];
  if (threadIdx.x < 4)  hp[threadIdx.x] = p.Hpost[(size_t)u*4+threadIdx.x];
  __syncthreads();
  for (int d = threadIdx.x; d < D_; d += 256){
    float yv = p.y[(size_t)u*D_ + d];
    float sm0 = p.stream[(((size_t)(b*N_+0)*T_)+t)*D_ + d];
    float sm1 = p.stream[(((size_t)(b*N_+1)*T_)+t)*D_ + d];
    float sm2 = p.stream[(((size_t)(b*N_+2)*T_)+t)*D_ + d];
    float sm3 = p.stream[(((size_t)(b*N_+3)*T_)+t)*D_ + d];
    #pragma unroll
    for (int n=0;n<4;n++){
      float v = hr[n*4+0]*sm0 + hr[n*4+1]*sm1 + hr[n*4+2]*sm2 + hr[n*4+3]*sm3 + hp[n]*yv;
      p.out[(((size_t)(b*N_+n)*T_)+t)*D_ + d] = v;
    }
  }
}

extern "C" void kernel_launch(void* const* d_in, const int* in_sizes, int n_in,
                              void* d_out, int out_size, void* d_ws, size_t ws_size,
                              hipStream_t stream){
  P p;
  p.stream = (const float*)d_in[0];
  p.freqs = (const float*)d_in[1];
  p.pope_delta = (const float*)d_in[2];
  p.W_q = (const float*)d_in[3]; p.W_k = (const float*)d_in[4]; p.W_v = (const float*)d_in[5];
  p.q_rw = (const float*)d_in[6]; p.kv_rw = (const float*)d_in[7];
  p.lA_q = (const float*)d_in[8];  p.lB_q = (const float*)d_in[9];
  p.lA_k = (const float*)d_in[10]; p.lB_k = (const float*)d_in[11];
  p.lA_v = (const float*)d_in[12]; p.lB_v = (const float*)d_in[13];
  p.a_up = (const float*)d_in[14]; p.a_dn = (const float*)d_in[15];
  p.b_up = (const float*)d_in[16]; p.b_dn = (const float*)d_in[17];
  p.mhc_norm = (const float*)d_in[18];
  p.phi_pre = (const float*)d_in[19]; p.phi_post = (const float*)d_in[20]; p.phi_res = (const float*)d_in[21];
  p.b_pre = (const float*)d_in[22]; p.b_post = (const float*)d_in[23]; p.b_res = (const float*)d_in[24];
  p.al_pre = (const float*)d_in[25]; p.al_post = (const float*)d_in[26]; p.al_res = (const float*)d_in[27];
  p.bn_w = (const float*)d_in[28];
  p.W_pre = (const float*)d_in[29]; p.W_o = (const float*)d_in[30];
  p.W_pg1 = (const float*)d_in[31]; p.W_pg2 = (const float*)d_in[32];
  p.out = (float*)d_out;

  char* w = (char*)d_ws;
  size_t off = 0;
  auto alloc = [&](size_t bytes)->void*{
    void* r = w + off;
    off = (off + bytes + 255) & ~(size_t)255;
    return r;
  };
  p.qsel   = (int*)alloc(H_*U_*4);
  p.kvsel  = (int*)alloc(H_*U_*4);
  p.qcnt   = (int*)alloc(HE_*4);
  p.kvcnt  = (int*)alloc(HE_*4);
  p.qlist  = (int*)alloc(HE_*U_*4);
  p.kvlist = (int*)alloc(HE_*U_*4);
  p.scale  = (float*)alloc(U_*4);
  p.phiT   = (float*)alloc((size_t)ND_*1152*4);
  p.mhc_logits = (float*)alloc((size_t)U_*1152*4);
  p.Hpre_q  = (float*)alloc((size_t)H_*U_*4*4);
  p.Hpre_kv = (float*)alloc((size_t)H_*U_*4*4);
  p.Hres    = (float*)alloc((size_t)U_*16*4);
  p.Hpost   = (float*)alloc((size_t)U_*4*4);
  p.he_kv   = (float*)alloc((size_t)H_*U_*D_*4);
  p.he_q    = (float*)alloc((size_t)H_*U_*D_*4);
  p.WqT     = (float*)alloc((size_t)H_*D_*64*4);
  p.WkT     = (float*)alloc((size_t)H_*D_*64*4);
  p.WvT     = (float*)alloc((size_t)H_*D_*64*4);
  p.WoT     = (float*)alloc((size_t)CC_*D_*4);
  p.kv_lin  = (float*)alloc((size_t)H_*U_*128*4);
  p.aup     = (float*)alloc((size_t)H_*U_*DA_*4);
  p.bup     = (float*)alloc((size_t)H_*U_*DA_*4);
  p.pre_logit  = (float*)alloc((size_t)U_*CC_*4);
  p.pg         = (float*)alloc((size_t)H_*U_*DPG_*4);
  p.post_logit = (float*)alloc((size_t)U_*D_*4);
  p.la_k    = (float*)alloc((size_t)H_*U_*R_*4);
  p.la_v    = (float*)alloc((size_t)H_*U_*R_*4);
  p.la_q    = (float*)alloc((size_t)H_*U_*R_*4);
  p.q_lin   = (float*)alloc((size_t)H_*U_*64*4);
  p.a_buf   = (float*)alloc((size_t)H_*U_*DKP_*4);
  p.b_buf   = (float*)alloc((size_t)H_*U_*4);
  p.q_buf   = (float*)alloc((size_t)H_*U_*DKP_*4);
  p.k_buf   = (float*)alloc((size_t)H_*U_*DKP_*4);
  p.v_buf   = (float*)alloc((size_t)H_*U_*DV_*4);
  p.attn    = (float*)alloc((size_t)U_*CC_*4);
  p.g       = (float*)alloc((size_t)U_*CC_*4);
  p.y       = (float*)alloc((size_t)U_*D_*4);
  if (off > ws_size) return;   // workspace too small -> fail validation cleanly

  hipMemsetAsync(p.qcnt, 0, HE_*4, stream);
  hipMemsetAsync(p.kvcnt, 0, HE_*4, stream);
  hipMemsetAsync(p.pre_logit, 0, (size_t)U_*CC_*4, stream);
  hipMemsetAsync(p.post_logit, 0, (size_t)U_*D_*4, stream);

  k_tr<<<dim3(8,(64*1024+255)/256),256,0,stream>>>(p.W_q, p.WqT, 64, 1024);
  k_tr<<<dim3(8,(64*1024+255)/256),256,0,stream>>>(p.W_k, p.WkT, 64, 1024);
  k_tr<<<dim3(8,(64*1024+255)/256),256,0,stream>>>(p.W_v, p.WvT, 64, 1024);
  k_tr<<<dim3(1,(1024*512+255)/256),256,0,stream>>>(p.W_o, p.WoT, 1024, 512);
  k_phiT<<<1152,256,0,stream>>>(p);
  k_route<<<U_,256,0,stream>>>(p);
  k_xscale<<<U_,256,0,stream>>>(p);
  k_gemm<0><<<dim3(18,16,1),256,0,stream>>>(p);
  k_mhcsel<<<U_,64,0,stream>>>(p);
  k_he<<<2*H_*U_,256,0,stream>>>(p);
  k_gemm<1><<<dim3(19,16,48),256,0,stream>>>(p);
  k_gemm<2><<<dim3(2,16,48),256,0,stream>>>(p);
  k_stage2<<<H_*U_,128,0,stream>>>(p);
  k_stage2q<<<H_*U_,64,0,stream>>>(p);
  k_gemm<3><<<dim3(16,16,48),256,0,stream>>>(p);
  k_scan<<<16,512,0,stream>>>(p);
  k_g<<<(U_*CC_+255)/256,256,0,stream>>>(p);
  k_gemm<4><<<dim3(16,16,1),256,0,stream>>>(p);
  k_final<<<U_,256,0,stream>>>(p);
}